// Round 14
// baseline (618.287 us; speedup 1.0000x reference)
//
#include <hip/hip_runtime.h>
#include <hip/hip_bf16.h>

#define D_DIM 1024
#define VOCABSZ 32000
#define NROWSZ 4096
#define MBLK 64
#define LOG2E 1.44269504088896340736f

typedef unsigned short u16;
typedef short s8v __attribute__((ext_vector_type(8)));
typedef short s4v __attribute__((ext_vector_type(4)));
typedef float f4v __attribute__((ext_vector_type(4)));
typedef __attribute__((address_space(3))) const char* lds_p3;

static __device__ __forceinline__ u16 f2bf(float f) {
  union { float f; unsigned int u; } x; x.f = f;
  unsigned int r = x.u + 0x7fffu + ((x.u >> 16) & 1u);
  return (u16)(r >> 16);
}
static __device__ __forceinline__ unsigned int pack2(float lo, float hi) {
  return (unsigned int)f2bf(lo) | ((unsigned int)f2bf(hi) << 16);
}
static __device__ __forceinline__ unsigned int pk_rn(float lo, float hi) {
  float2 f; f.x = lo; f.y = hi;
  union { __hip_bfloat162 h; unsigned int u; } v;
  v.h = __float22bfloat162_rn(f);
  return v.u;
}
#define EXP2(x) __builtin_amdgcn_exp2f(x)

static __device__ __forceinline__ float bf2f(u16 b) {
  union { unsigned int u; float f; } x; x.u = ((unsigned int)b) << 16;
  return x.f;
}
static __device__ __forceinline__ float bfu_lo(unsigned int u) {
  union { unsigned int u; float f; } x; x.u = u << 16; return x.f;
}
static __device__ __forceinline__ float bfu_hi(unsigned int u) {
  union { unsigned int u; float f; } x; x.u = u & 0xffff0000u; return x.f;
}
static __device__ __forceinline__ f4v MFMA(s8v a, s8v b, f4v c) {
  return __builtin_amdgcn_mfma_f32_16x16x32_bf16(a, b, c, 0, 0, 0);
}

#define GLOAD_LDS16(gp, lp)                                                  \
  __builtin_amdgcn_global_load_lds(                                         \
      (const __attribute__((address_space(1))) void*)(gp),                  \
      (__attribute__((address_space(3))) void*)(lp), 16, 0, 0)

// ---------------------------------------------------------------------------
// Prep: emb fp32 -> ETt: per 32-vocab tile, a 64 KB subtiled image:
//   byte(v,d) = ((v>>2)*64 + (d>>4))*128 + (v&3)*32 + (d&15)*2
// QK A-frags = contiguous 16B rows; PV B-frags via ds_read_b64_tr_b16.
// ---------------------------------------------------------------------------
__global__ __launch_bounds__(256) void cvt3_kernel(const float* __restrict__ emb,
                                                   char* __restrict__ ETt) {
  const int b = blockIdx.x, t = threadIdx.x;
  const int v0 = b * 32;
  char* outp = ETt + ((size_t)b << 16);
#pragma unroll
  for (int k = 0; k < 16; ++k) {
    int ci = t + 256 * k;       // 0..4095
    int v = ci >> 7;            // 0..31
    int d8 = ci & 127;          // d = 8*d8
    const float* s = emb + (size_t)(v0 + v) * D_DIM + d8 * 8;
    float4 a = *(const float4*)s;
    float4 bb = *(const float4*)(s + 4);
    uint4 x;
    x.x = pack2(a.x, a.y); x.y = pack2(a.z, a.w);
    x.z = pack2(bb.x, bb.y); x.w = pack2(bb.z, bb.w);
    int off = ((v >> 2) * 64 + (d8 >> 1)) * 128 + (v & 3) * 32 + (d8 & 1) * 16;
    *(uint4*)(outp + off) = x;
  }
}

// ---------------------------------------------------------------------------
// Flash v14: staggered wave groups. G0 = waves 0-3 (rows 0-31), G1 = waves
// 4-7 (rows 32-63); data-independent (disjoint Sred quadrants / P halves).
// G1 runs one phase behind G0 so each barrier window pairs MFMA/LDS work of
// one group with VALU work of the other (per-SIMD pipe overlap, m114):
//   W1: G0 QK(t)  | G1 PV(t-1)
//   W2: G0 SM(t)  | G1 QK(t)
//   W3: G0 PV(t)  | G1 SM(t)
// STAGE(t+1) after B2, drained at next-iter B0 (flight = W3). Only B0 ever
// has DMA in flight. Phase bodies = v9's proven code, parameterized by mh.
// ---------------------------------------------------------------------------
template <int NSPLIT>
__global__ __launch_bounds__(512, 2) void flash14_kernel(
    const float* __restrict__ qg, const char* __restrict__ ETt,
    float* __restrict__ out, u16* __restrict__ pctx, float* __restrict__ pstat) {
  __shared__ char ring[2 * 65536];      // 128 KB: E-tile ring (subtiled image)
  __shared__ uint2 Sred[8 * 4 * 64];    // 16 KB: bf16x4 S^T partials
  __shared__ char Plds[4096];           // 4 KB: P [mh][32 m][32 v] bf16
  __shared__ float lred[8][16];

  const int tid = threadIdx.x;
  const int w = tid >> 6;
  const int l = tid & 63;
  const int g = l >> 4;
  const int c = l & 15;
  const int ds = w & 3;                 // d-slice: [ds*256, ds*256+256)
  const int mh = w >> 2;                // m-half: rows [mh*32, mh*32+32)
  const int bid = blockIdx.x;
  const int sp = (NSPLIT == 4) ? (bid & 3) : 0;
  const int rb = (NSPLIT == 4) ? (bid >> 2) : bid;
  const int row0 = rb * MBLK;
  const int vslice = VOCABSZ / NSPLIT;
  const int ntiles = vslice / 32;       // 250 or 1000
  const int gt0 = sp * ntiles;

  const f4v fzero = {0.f, 0.f, 0.f, 0.f};

  // ---- Q fragments (B-role), pre-scaled by LOG2E so softmax is exp2-direct.
  s8v qf[2][8];
#pragma unroll
  for (int mt = 0; mt < 2; ++mt)
#pragma unroll
    for (int kt = 0; kt < 8; ++kt) {
      const float* src = qg + (size_t)(row0 + mh * 32 + 16 * mt + c) * D_DIM +
                         ds * 256 + 32 * kt + 8 * g;
      float4 a = *(const float4*)src;
      float4 b = *(const float4*)(src + 4);
      s8v v;
      v[0] = (short)f2bf(a.x * LOG2E); v[1] = (short)f2bf(a.y * LOG2E);
      v[2] = (short)f2bf(a.z * LOG2E); v[3] = (short)f2bf(a.w * LOG2E);
      v[4] = (short)f2bf(b.x * LOG2E); v[5] = (short)f2bf(b.y * LOG2E);
      v[6] = (short)f2bf(b.z * LOG2E); v[7] = (short)f2bf(b.w * LOG2E);
      qf[mt][kt] = v;
    }

  f4v acc[2][16];
#pragma unroll
  for (int mt = 0; mt < 2; ++mt)
#pragma unroll
    for (int nt = 0; nt < 16; ++nt) acc[mt][nt] = fzero;

  float lcur = 0.f;
  const int pab_s = mh * 2048 + c * 64 + g * 16;
  const int abase_s = ((2 * g) * 64 + 16 * ds) * 128 + c * 2;

#define STAGE(U)                                                             \
  {                                                                          \
    const char* _gs = ETt + (((size_t)(gt0 + (U))) << 16) + tid * 16;        \
    char* _ls = ring + (((U) & 1) << 16) + tid * 16;                         \
    _Pragma("unroll") for (int _j = 0; _j < 8; ++_j)                         \
        GLOAD_LDS16(_gs + _j * 8192, _ls + _j * 8192);                       \
  }

  // v9's QK body: S^T partial over this wave's 256-d slice -> Sred quadrants.
#define QK_STEP(BUF)                                                         \
  {                                                                          \
    _Pragma("unroll") for (int vt = 0; vt < 2; ++vt) {                       \
      const char* bp = (BUF) +                                               \
          (((4 * vt + (c >> 2)) * 64 + 16 * ds + (g >> 1)) * 128 +           \
           (c & 3) * 32 + (g & 1) * 16);                                     \
      f4v st0 = fzero, st1 = fzero;                                          \
      _Pragma("unroll") for (int kt = 0; kt < 8; ++kt) {                     \
        s8v ek = *(const s8v*)(bp + kt * 256);                               \
        st0 = MFMA(ek, qf[0][kt], st0);                                      \
        st1 = MFMA(ek, qf[1][kt], st1);                                      \
      }                                                                      \
      int qb = ((mh * 4 + vt * 2) * 4 + ds) * 64 + l;                        \
      uint2 pk;                                                              \
      pk.x = pk_rn(st0[0], st0[1]); pk.y = pk_rn(st0[2], st0[3]);            \
      Sred[qb] = pk;                                                         \
      pk.x = pk_rn(st1[0], st1[1]); pk.y = pk_rn(st1[2], st1[3]);            \
      Sred[qb + 256] = pk;                                                   \
    }                                                                        \
  }

  // v9's softmax body: own quadrant reduce + exp + P write + lcur.
#define SM_STEP()                                                            \
  {                                                                          \
    int qq = mh * 4 + ds;                                                    \
    f4v ss = fzero;                                                          \
    _Pragma("unroll") for (int ww = 0; ww < 4; ++ww) {                       \
      uint2 u = Sred[(qq * 4 + ww) * 64 + l];                                \
      ss[0] += bfu_lo(u.x); ss[1] += bfu_hi(u.x);                            \
      ss[2] += bfu_lo(u.y); ss[3] += bfu_hi(u.y);                            \
    }                                                                        \
    float p0 = EXP2(ss[0]), p1 = EXP2(ss[1]);                                \
    float p2 = EXP2(ss[2]), p3 = EXP2(ss[3]);                                \
    int pb = mh * 2048 + (16 * (ds & 1) + c) * 64 +                          \
             (16 * (ds >> 1) + 4 * g) * 2;                                   \
    uint2 pw; pw.x = pk_rn(p0, p1); pw.y = pk_rn(p2, p3);                    \
    *(uint2*)(Plds + pb) = pw;                                               \
    lcur += (p0 + p1) + (p2 + p3);                                           \
  }

  // v9's PV body: A = P rows (b128), B = E^T via batched tr-reads.
#define PV_STEP(BUF)                                                         \
  {                                                                          \
    s8v pa0 = *(const s8v*)(Plds + pab_s);                                   \
    s8v pa1 = *(const s8v*)(Plds + pab_s + 1024);                            \
    const char* ab = (BUF) + abase_s;                                        \
    _Pragma("unroll") for (int bb = 0; bb < 2; ++bb) {                       \
      s4v trv[16];                                                           \
      _Pragma("unroll") for (int k = 0; k < 8; ++k) {                        \
        int nt = bb * 8 + k;                                                 \
        const char* a0 = ab + nt * 128;                                      \
        asm volatile("ds_read_b64_tr_b16 %0, %1"                             \
                     : "=v"(trv[2 * k]) : "v"((lds_p3)a0));                  \
        asm volatile("ds_read_b64_tr_b16 %0, %1"                             \
                     : "=v"(trv[2 * k + 1]) : "v"((lds_p3)(a0 + 8192)));     \
      }                                                                      \
      asm volatile("s_waitcnt lgkmcnt(0)" ::: "memory");                     \
      __builtin_amdgcn_sched_barrier(0);                                     \
      _Pragma("unroll") for (int k = 0; k < 8; ++k) {                        \
        int nt = bb * 8 + k;                                                 \
        union { s4v s[2]; s8v v; } ev;                                       \
        ev.s[0] = trv[2 * k]; ev.s[1] = trv[2 * k + 1];                      \
        acc[0][nt] = MFMA(pa0, ev.v, acc[0][nt]);                            \
        acc[1][nt] = MFMA(pa1, ev.v, acc[1][nt]);                            \
      }                                                                      \
    }                                                                        \
  }

  // prologue: tile 0 staged; first B0 drains it.
  STAGE(0);

  for (int t = 0; t < ntiles; ++t) {
    const char* buf = ring + ((t & 1) << 16);
    const char* bufp = ring + (((t - 1) & 1) << 16);

    __syncthreads();                   // B0: stage(t) DMA drained for all waves

    // ---- W1: G0 QK(t) | G1 PV(t-1)
    if (mh == 0) {
      QK_STEP(buf);
    } else if (t > 0) {
      PV_STEP(bufp);
    }
    __syncthreads();                   // B1

    // ---- W2: G0 SM(t) | G1 QK(t)
    if (mh == 0) {
      SM_STEP();
    } else {
      QK_STEP(buf);
    }
    __syncthreads();                   // B2

    if (t + 1 < ntiles) STAGE(t + 1);  // flight = W3, drained at next B0

    // ---- W3: G0 PV(t) | G1 SM(t)
    if (mh == 0) {
      PV_STEP(buf);
    } else {
      SM_STEP();
    }
  }
  // ---- epilogue: G1's PV of the last tile (ring slot untouched since)
  __syncthreads();
  if (mh == 1) {
    const char* bufl = ring + (((ntiles - 1) & 1) << 16);
    PV_STEP(bufl);
  }
#undef STAGE
#undef QK_STEP
#undef SM_STEP
#undef PV_STEP

  // ---- finalize: deferred row-sum reduction, then normalize+write
  {
    float lp = lcur;
    lp += __shfl_xor(lp, 16);
    lp += __shfl_xor(lp, 32);
    __syncthreads();
    if (g == 0) lred[mh * 4 + ds][c] = lp;
  }
  __syncthreads();

  if (NSPLIT == 1) {
#pragma unroll
    for (int mt = 0; mt < 2; ++mt) {
      float inv[4];
#pragma unroll
      for (int r = 0; r < 4; ++r)
        inv[r] = 1.f / (lred[mh * 4 + mt][4 * g + r] + lred[mh * 4 + 2 + mt][4 * g + r]);
#pragma unroll
      for (int nt = 0; nt < 16; ++nt)
#pragma unroll
        for (int r = 0; r < 4; ++r) {
          size_t o = (size_t)(row0 + mh * 32 + 16 * mt + 4 * g + r) * D_DIM +
                     ds * 256 + 16 * nt + c;
          out[o] = acc[mt][nt][r] * inv[r] + qg[o];
        }
    }
  } else {
    u16* pc = pctx + (size_t)sp * NROWSZ * D_DIM;
#pragma unroll
    for (int mt = 0; mt < 2; ++mt)
#pragma unroll
      for (int nt = 0; nt < 16; ++nt)
#pragma unroll
        for (int r = 0; r < 4; ++r)
          pc[(size_t)(row0 + mh * 32 + 16 * mt + 4 * g + r) * D_DIM +
             ds * 256 + 16 * nt + c] = f2bf(acc[mt][nt][r]);
    if (ds < 2 && g == 0)
      pstat[(size_t)sp * NROWSZ + row0 + mh * 32 + 16 * ds + c] =
          lred[mh * 4 + ds][c] + lred[mh * 4 + 2 + ds][c];
  }
}

// ---------------------------------------------------------------------------
// Combine NSPLIT=4 partials: out = (sum ctx_sp) / (sum l_sp) + q
// ---------------------------------------------------------------------------
__global__ __launch_bounds__(256) void combine2_kernel(const float* __restrict__ qg,
                                                       const u16* __restrict__ pctx,
                                                       const float* __restrict__ pstat,
                                                       float* __restrict__ out) {
  const int r = blockIdx.x;
  const int t = threadIdx.x;
  float L = pstat[r] + pstat[NROWSZ + r] + pstat[2 * NROWSZ + r] + pstat[3 * NROWSZ + r];
  float inv = 1.f / L;
  size_t o = (size_t)r * D_DIM + t * 4;
  float sx = 0.f, sy = 0.f, sz = 0.f, sw = 0.f;
#pragma unroll
  for (int sp = 0; sp < 4; ++sp) {
    ushort4 u = *(const ushort4*)(pctx + (size_t)sp * NROWSZ * D_DIM + o);
    sx += bf2f(u.x); sy += bf2f(u.y); sz += bf2f(u.z); sw += bf2f(u.w);
  }
  float4 qv = *(const float4*)(qg + o);
  float4 res;
  res.x = sx * inv + qv.x;
  res.y = sy * inv + qv.y;
  res.z = sz * inv + qv.z;
  res.w = sw * inv + qv.w;
  *(float4*)(out + o) = res;
}

// ---------------------------------------------------------------------------
// Naive correctness fallback (tiny ws): one q-row per block.
// ---------------------------------------------------------------------------
__global__ __launch_bounds__(256) void naive_kernel(const float* __restrict__ qg,
                                                    const float* __restrict__ emb,
                                                    float* __restrict__ out) {
  __shared__ float s[VOCABSZ];
  __shared__ float qrow[D_DIM];
  __shared__ float lsh[4];
  const int r = blockIdx.x;
  const int t = threadIdx.x;
  for (int i = t; i < D_DIM; i += 256) qrow[i] = qg[(size_t)r * D_DIM + i];
  __syncthreads();
  float lpart = 0.f;
  for (int v = t; v < VOCABSZ; v += 256) {
    float dot = 0.f;
    for (int d = 0; d < D_DIM; d += 4) {
      float4 e = *(const float4*)(emb + (size_t)v * D_DIM + d);
      dot += qrow[d] * e.x + qrow[d + 1] * e.y + qrow[d + 2] * e.z + qrow[d + 3] * e.w;
    }
    float p = exp2f(dot * LOG2E);
    s[v] = p;
    lpart += p;
  }
  for (int o = 32; o; o >>= 1) lpart += __shfl_xor(lpart, o);
  if ((t & 63) == 0) lsh[t >> 6] = lpart;
  __syncthreads();
  float inv = 1.f / (lsh[0] + lsh[1] + lsh[2] + lsh[3]);
  float ax = 0.f, ay = 0.f, az = 0.f, aw = 0.f;
  for (int v = 0; v < VOCABSZ; ++v) {
    float p = s[v];
    float4 e = *(const float4*)(emb + (size_t)v * D_DIM + t * 4);
    ax += p * e.x; ay += p * e.y; az += p * e.z; aw += p * e.w;
  }
  size_t o = (size_t)r * D_DIM + t * 4;
  float4 qv = *(const float4*)(qg + o);
  float4 res;
  res.x = ax * inv + qv.x;
  res.y = ay * inv + qv.y;
  res.z = az * inv + qv.z;
  res.w = aw * inv + qv.w;
  *(float4*)(out + o) = res;
}

extern "C" void kernel_launch(void* const* d_in, const int* in_sizes, int n_in,
                              void* d_out, int out_size, void* d_ws, size_t ws_size,
                              hipStream_t stream) {
  const float* q = (const float*)d_in[0];
  const float* emb = (const float*)d_in[1];
  float* out = (float*)d_out;
  char* ws = (char*)d_ws;

  const size_t ETT_BYTES = 65536000ull;                      // 1000 tiles x 64 KB
  const size_t PCTX_BYTES = 4ull * NROWSZ * D_DIM * 2;       // 33,554,432
  const size_t PSTAT_BYTES = 4ull * NROWSZ * 4;              // 65,536

  if (ws_size >= ETT_BYTES + PCTX_BYTES + PSTAT_BYTES) {     // 99,155,968
    char* ETt = ws;
    u16* pctx = (u16*)(ws + ETT_BYTES);
    float* pstat = (float*)(ws + ETT_BYTES + PCTX_BYTES);
    cvt3_kernel<<<VOCABSZ / 32, 256, 0, stream>>>(emb, ETt);
    flash14_kernel<4><<<256, 512, 0, stream>>>(q, ETt, out, pctx, pstat);
    combine2_kernel<<<NROWSZ, 256, 0, stream>>>(q, pctx, pstat, out);
  } else if (ws_size >= ETT_BYTES) {
    char* ETt = ws;
    cvt3_kernel<<<VOCABSZ / 32, 256, 0, stream>>>(emb, ETt);
    flash14_kernel<1><<<NROWSZ / MBLK, 512, 0, stream>>>(q, ETt, out, nullptr, nullptr);
  } else {
    naive_kernel<<<NROWSZ, 256, 0, stream>>>(q, emb, out);
  }
}

// Round 15
// 592.921 us; speedup vs baseline: 1.0428x; 1.0428x over previous
//
#include <hip/hip_runtime.h>
#include <hip/hip_bf16.h>

#define D_DIM 1024
#define VOCABSZ 32000
#define NROWSZ 4096
#define MBLK 64
#define LOG2E 1.44269504088896340736f

typedef unsigned short u16;
typedef short s8v __attribute__((ext_vector_type(8)));
typedef short s4v __attribute__((ext_vector_type(4)));
typedef float f4v __attribute__((ext_vector_type(4)));
typedef __attribute__((address_space(3))) const char* lds_p3;

static __device__ __forceinline__ u16 f2bf(float f) {
  union { float f; unsigned int u; } x; x.f = f;
  unsigned int r = x.u + 0x7fffu + ((x.u >> 16) & 1u);
  return (u16)(r >> 16);
}
static __device__ __forceinline__ unsigned int pack2(float lo, float hi) {
  return (unsigned int)f2bf(lo) | ((unsigned int)f2bf(hi) << 16);
}
static __device__ __forceinline__ unsigned int pk_rn(float lo, float hi) {
  float2 f; f.x = lo; f.y = hi;
  union { __hip_bfloat162 h; unsigned int u; } v;
  v.h = __float22bfloat162_rn(f);
  return v.u;
}
#define EXP2(x) __builtin_amdgcn_exp2f(x)

static __device__ __forceinline__ float bf2f(u16 b) {
  union { unsigned int u; float f; } x; x.u = ((unsigned int)b) << 16;
  return x.f;
}
static __device__ __forceinline__ float bfu_lo(unsigned int u) {
  union { unsigned int u; float f; } x; x.u = u << 16; return x.f;
}
static __device__ __forceinline__ float bfu_hi(unsigned int u) {
  union { unsigned int u; float f; } x; x.u = u & 0xffff0000u; return x.f;
}
static __device__ __forceinline__ f4v MFMA(s8v a, s8v b, f4v c) {
  return __builtin_amdgcn_mfma_f32_16x16x32_bf16(a, b, c, 0, 0, 0);
}

#define GLOAD_LDS16(gp, lp)                                                  \
  __builtin_amdgcn_global_load_lds(                                         \
      (const __attribute__((address_space(1))) void*)(gp),                  \
      (__attribute__((address_space(3))) void*)(lp), 16, 0, 0)

// ---------------------------------------------------------------------------
// Prep: emb fp32 -> ETt: per 32-vocab tile, a 64 KB subtiled image:
//   byte(v,d) = ((v>>2)*64 + (d>>4))*128 + (v&3)*32 + (d&15)*2
// (unchanged, proven) QK A-frags = contiguous 16B rows; PV via tr-reads.
// ---------------------------------------------------------------------------
__global__ __launch_bounds__(256) void cvt3_kernel(const float* __restrict__ emb,
                                                   char* __restrict__ ETt) {
  const int b = blockIdx.x, t = threadIdx.x;
  const int v0 = b * 32;
  char* outp = ETt + ((size_t)b << 16);
#pragma unroll
  for (int k = 0; k < 16; ++k) {
    int ci = t + 256 * k;
    int v = ci >> 7;
    int d8 = ci & 127;
    const float* s = emb + (size_t)(v0 + v) * D_DIM + d8 * 8;
    float4 a = *(const float4*)s;
    float4 bb = *(const float4*)(s + 4);
    uint4 x;
    x.x = pack2(a.x, a.y); x.y = pack2(a.z, a.w);
    x.z = pack2(bb.x, bb.y); x.w = pack2(bb.z, bb.w);
    int off = ((v >> 2) * 64 + (d8 >> 1)) * 128 + (v & 3) * 32 + (d8 & 1) * 16;
    *(uint4*)(outp + off) = x;
  }
}

// ---------------------------------------------------------------------------
// Flash v15: all-m wave decomposition. 8 waves = 8 x (128-d slice x ALL 64
// rows). Each E byte read ONCE per CU (was twice): QK b128 ops 128->64,
// tr ops 256->128. Schedule = v9's proven 2-barrier loop + post-B2 STAGE.
// Sred: each wave keeps its OWN quadrant (q==w) in registers; 7 others in
// LDS [8 q][7 slots][64] = 28 KB (diagonal-skip). lred aliased into Sred
// post-loop. P [64 m][32 v] with 2-way-free slot swizzle
// ((c&3)^((c>>2)&1))<<4. LDS total = 128K ring + 28K + 4K = 160 KiB exact.
// ---------------------------------------------------------------------------
template <int NSPLIT>
__global__ __launch_bounds__(512, 2) void flash15_kernel(
    const float* __restrict__ qg, const char* __restrict__ ETt,
    float* __restrict__ out, u16* __restrict__ pctx, float* __restrict__ pstat) {
  __shared__ char ring[2 * 65536];      // 128 KB: E-tile ring (subtiled image)
  __shared__ uint2 Sred[8 * 7 * 64];    // 28 KB: bf16x4 S^T partials (off-diag)
  __shared__ char Plds[4096];           // 4 KB: P [64 m][32 v] bf16, swizzled

  const int tid = threadIdx.x;
  const int w = tid >> 6;               // wave = d-slice [w*128, w*128+128)
  const int l = tid & 63;
  const int g = l >> 4;
  const int c = l & 15;
  const int bid = blockIdx.x;
  const int sp = (NSPLIT == 4) ? (bid & 3) : 0;
  const int rb = (NSPLIT == 4) ? (bid >> 2) : bid;
  const int row0 = rb * MBLK;
  const int vslice = VOCABSZ / NSPLIT;
  const int ntiles = vslice / 32;
  const int gt0 = sp * ntiles;

  const f4v fzero = {0.f, 0.f, 0.f, 0.f};
  // P slot swizzle: slot = ((c&3)^((c>>2)&1)); 16 lanes -> 8 half-window
  // slots x 2 lanes = 2-way (free, m136). Same value on write & read side.
  const int swzP = (((c & 3) ^ ((c >> 2) & 1)) << 4);

  // ---- Q fragments (B-role): qf[mt][kt] = Q[row0+16mt+c][w*128+32kt+8g+i]
  s8v qf[4][4];
#pragma unroll
  for (int mt = 0; mt < 4; ++mt)
#pragma unroll
    for (int kt = 0; kt < 4; ++kt) {
      const float* src = qg + (size_t)(row0 + 16 * mt + c) * D_DIM +
                         w * 128 + 32 * kt + 8 * g;
      float4 a = *(const float4*)src;
      float4 b = *(const float4*)(src + 4);
      s8v v;
      v[0] = (short)f2bf(a.x * LOG2E); v[1] = (short)f2bf(a.y * LOG2E);
      v[2] = (short)f2bf(a.z * LOG2E); v[3] = (short)f2bf(a.w * LOG2E);
      v[4] = (short)f2bf(b.x * LOG2E); v[5] = (short)f2bf(b.y * LOG2E);
      v[6] = (short)f2bf(b.z * LOG2E); v[7] = (short)f2bf(b.w * LOG2E);
      qf[mt][kt] = v;
    }

  f4v acc[4][8];
#pragma unroll
  for (int mt = 0; mt < 4; ++mt)
#pragma unroll
    for (int nt = 0; nt < 8; ++nt) acc[mt][nt] = fzero;

  f4v ssown = fzero;                    // own quadrant (q==w) partial, f32
  float lcur = 0.f;

#define STAGE(U)                                                             \
  {                                                                          \
    const char* _gs = ETt + (((size_t)(gt0 + (U))) << 16) + tid * 16;        \
    char* _ls = ring + (((U) & 1) << 16) + tid * 16;                         \
    _Pragma("unroll") for (int _j = 0; _j < 8; ++_j)                         \
        GLOAD_LDS16(_gs + _j * 8192, _ls + _j * 8192);                       \
  }

  // prologue: tile 0 staged and drained (syncthreads emits vmcnt(0))
  STAGE(0);
  __syncthreads();

  for (int t = 0; t < ntiles; ++t) {
    const char* buf = ring + ((t & 1) << 16);

    // ================= QK: full S^T partial over this wave's 128-d slice ====
    // A-frag E[v=16vt+c][d], shared across 4 mt -> 4:1 MFMA:b128 ratio.
#pragma unroll
    for (int vt = 0; vt < 2; ++vt) {
      const char* bp = buf + (((4 * vt + (c >> 2)) * 64 + 8 * w + (g >> 1)) * 128 +
                              (c & 3) * 32 + (g & 1) * 16);
      f4v st[4];
      st[0] = fzero; st[1] = fzero; st[2] = fzero; st[3] = fzero;
#pragma unroll
      for (int kt = 0; kt < 4; ++kt) {
        s8v ek = *(const s8v*)(bp + kt * 256);
        st[0] = MFMA(ek, qf[0][kt], st[0]);
        st[1] = MFMA(ek, qf[1][kt], st[1]);
        st[2] = MFMA(ek, qf[2][kt], st[2]);
        st[3] = MFMA(ek, qf[3][kt], st[3]);
      }
#pragma unroll
      for (int mt = 0; mt < 4; ++mt) {
        const int q = vt * 4 + mt;
        if (q == w) {
          ssown = st[mt];               // diagonal: keep in registers
        } else {
          int slot = w - (w > q ? 1 : 0);
          uint2 pk;
          pk.x = pk_rn(st[mt][0], st[mt][1]);
          pk.y = pk_rn(st[mt][2], st[mt][3]);
          Sred[(q * 7 + slot) * 64 + l] = pk;
        }
      }
    }
    __syncthreads();                    // B1: Sred visible; drains STAGE DMA
                                        // (issued a full PV-phase ago -> hidden)

    // ================= softmax: wave w owns quadrant q=w (vt=w>>2, mt=w&3) ==
    {
      f4v ss = ssown;
#pragma unroll
      for (int s = 0; s < 7; ++s) {
        uint2 u = Sred[(w * 7 + s) * 64 + l];
        ss[0] += bfu_lo(u.x); ss[1] += bfu_hi(u.x);
        ss[2] += bfu_lo(u.y); ss[3] += bfu_hi(u.y);
      }
      float p0 = EXP2(ss[0]), p1 = EXP2(ss[1]);
      float p2 = EXP2(ss[2]), p3 = EXP2(ss[3]);
      int m_ = 16 * (w & 3) + c;
      int pb = m_ * 64 + ((32 * (w >> 2) + 8 * g) ^ swzP);
      uint2 pw; pw.x = pk_rn(p0, p1); pw.y = pk_rn(p2, p3);
      *(uint2*)(Plds + pb) = pw;
      lcur += (p0 + p1) + (p2 + p3);    // row-sum shfl deferred to epilogue
    }
    __syncthreads();                    // B2: P visible (no DMA in flight here)

    // stage next tile: in flight across PV + next QK (v9's proven margin)
    if (t + 1 < ntiles) STAGE(t + 1);

    // ================= PV: A = P rows (b128), B = E^T via tr-reads ==========
    {
      const int prb = c * 64 + ((16 * g) ^ swzP);
      s8v pa0 = *(const s8v*)(Plds + prb);
      s8v pa1 = *(const s8v*)(Plds + prb + 1024);
      s8v pa2 = *(const s8v*)(Plds + prb + 2048);
      s8v pa3 = *(const s8v*)(Plds + prb + 3072);
      const char* ab = buf + g * 16384 + w * 1024 + c * 2;
#pragma unroll
      for (int bb = 0; bb < 2; ++bb) {
        union uev { s4v s[2]; s8v v; } ev[4];
#pragma unroll
        for (int k = 0; k < 4; ++k) {
          const char* a0 = ab + (bb * 4 + k) * 128;
          asm volatile("ds_read_b64_tr_b16 %0, %1"
                       : "=v"(ev[k].s[0]) : "v"((lds_p3)a0));
          asm volatile("ds_read_b64_tr_b16 %0, %1"
                       : "=v"(ev[k].s[1]) : "v"((lds_p3)(a0 + 8192)));
        }
        asm volatile("s_waitcnt lgkmcnt(0)" ::: "memory");
        __builtin_amdgcn_sched_barrier(0);
#pragma unroll
        for (int k = 0; k < 4; ++k) {
          int nt = bb * 4 + k;
          acc[0][nt] = MFMA(pa0, ev[k].v, acc[0][nt]);
          acc[1][nt] = MFMA(pa1, ev[k].v, acc[1][nt]);
          acc[2][nt] = MFMA(pa2, ev[k].v, acc[2][nt]);
          acc[3][nt] = MFMA(pa3, ev[k].v, acc[3][nt]);
        }
      }
    }
  }
#undef STAGE

  // ---- finalize: deferred row-sum reduction (lred aliased into Sred)
  float* lredp = (float*)Sred;
  {
    float lp = lcur;
    lp += __shfl_xor(lp, 16);
    lp += __shfl_xor(lp, 32);
    __syncthreads();                    // last Sred reads long done
    if (g == 0) lredp[w * 16 + c] = lp;
  }
  __syncthreads();

  if (NSPLIT == 1) {
#pragma unroll
    for (int mt = 0; mt < 4; ++mt) {
      float inv[4];
#pragma unroll
      for (int r = 0; r < 4; ++r)
        inv[r] = 1.f / (lredp[mt * 16 + 4 * g + r] + lredp[(mt + 4) * 16 + 4 * g + r]);
#pragma unroll
      for (int nt = 0; nt < 8; ++nt)
#pragma unroll
        for (int r = 0; r < 4; ++r) {
          size_t o = (size_t)(row0 + 16 * mt + 4 * g + r) * D_DIM +
                     w * 128 + 16 * nt + c;
          out[o] = acc[mt][nt][r] * inv[r] + qg[o];
        }
    }
  } else {
    u16* pc = pctx + (size_t)sp * NROWSZ * D_DIM;
#pragma unroll
    for (int mt = 0; mt < 4; ++mt)
#pragma unroll
      for (int nt = 0; nt < 8; ++nt)
#pragma unroll
        for (int r = 0; r < 4; ++r)
          pc[(size_t)(row0 + 16 * mt + 4 * g + r) * D_DIM +
             w * 128 + 16 * nt + c] = f2bf(acc[mt][nt][r]);
    if (w < 4 && g == 0)
      pstat[(size_t)sp * NROWSZ + row0 + 16 * w + c] =
          lredp[w * 16 + c] + lredp[(w + 4) * 16 + c];
  }
}

// ---------------------------------------------------------------------------
// Combine NSPLIT=4 partials: out = (sum ctx_sp) / (sum l_sp) + q
// ---------------------------------------------------------------------------
__global__ __launch_bounds__(256) void combine2_kernel(const float* __restrict__ qg,
                                                       const u16* __restrict__ pctx,
                                                       const float* __restrict__ pstat,
                                                       float* __restrict__ out) {
  const int r = blockIdx.x;
  const int t = threadIdx.x;
  float L = pstat[r] + pstat[NROWSZ + r] + pstat[2 * NROWSZ + r] + pstat[3 * NROWSZ + r];
  float inv = 1.f / L;
  size_t o = (size_t)r * D_DIM + t * 4;
  float sx = 0.f, sy = 0.f, sz = 0.f, sw = 0.f;
#pragma unroll
  for (int sp = 0; sp < 4; ++sp) {
    ushort4 u = *(const ushort4*)(pctx + (size_t)sp * NROWSZ * D_DIM + o);
    sx += bf2f(u.x); sy += bf2f(u.y); sz += bf2f(u.z); sw += bf2f(u.w);
  }
  float4 qv = *(const float4*)(qg + o);
  float4 res;
  res.x = sx * inv + qv.x;
  res.y = sy * inv + qv.y;
  res.z = sz * inv + qv.z;
  res.w = sw * inv + qv.w;
  *(float4*)(out + o) = res;
}

// ---------------------------------------------------------------------------
// Naive correctness fallback (tiny ws): one q-row per block.
// ---------------------------------------------------------------------------
__global__ __launch_bounds__(256) void naive_kernel(const float* __restrict__ qg,
                                                    const float* __restrict__ emb,
                                                    float* __restrict__ out) {
  __shared__ float s[VOCABSZ];
  __shared__ float qrow[D_DIM];
  __shared__ float lsh[4];
  const int r = blockIdx.x;
  const int t = threadIdx.x;
  for (int i = t; i < D_DIM; i += 256) qrow[i] = qg[(size_t)r * D_DIM + i];
  __syncthreads();
  float lpart = 0.f;
  for (int v = t; v < VOCABSZ; v += 256) {
    float dot = 0.f;
    for (int d = 0; d < D_DIM; d += 4) {
      float4 e = *(const float4*)(emb + (size_t)v * D_DIM + d);
      dot += qrow[d] * e.x + qrow[d + 1] * e.y + qrow[d + 2] * e.z + qrow[d + 3] * e.w;
    }
    float p = exp2f(dot * LOG2E);
    s[v] = p;
    lpart += p;
  }
  for (int o = 32; o; o >>= 1) lpart += __shfl_xor(lpart, o);
  if ((t & 63) == 0) lsh[t >> 6] = lpart;
  __syncthreads();
  float inv = 1.f / (lsh[0] + lsh[1] + lsh[2] + lsh[3]);
  float ax = 0.f, ay = 0.f, az = 0.f, aw = 0.f;
  for (int v = 0; v < VOCABSZ; ++v) {
    float p = s[v];
    float4 e = *(const float4*)(emb + (size_t)v * D_DIM + t * 4);
    ax += p * e.x; ay += p * e.y; az += p * e.z; aw += p * e.w;
  }
  size_t o = (size_t)r * D_DIM + t * 4;
  float4 qv = *(const float4*)(qg + o);
  float4 res;
  res.x = ax * inv + qv.x;
  res.y = ay * inv + qv.y;
  res.z = az * inv + qv.z;
  res.w = aw * inv + qv.w;
  *(float4*)(out + o) = res;
}

extern "C" void kernel_launch(void* const* d_in, const int* in_sizes, int n_in,
                              void* d_out, int out_size, void* d_ws, size_t ws_size,
                              hipStream_t stream) {
  const float* q = (const float*)d_in[0];
  const float* emb = (const float*)d_in[1];
  float* out = (float*)d_out;
  char* ws = (char*)d_ws;

  const size_t ETT_BYTES = 65536000ull;                      // 1000 tiles x 64 KB
  const size_t PCTX_BYTES = 4ull * NROWSZ * D_DIM * 2;       // 33,554,432
  const size_t PSTAT_BYTES = 4ull * NROWSZ * 4;              // 65,536

  if (ws_size >= ETT_BYTES + PCTX_BYTES + PSTAT_BYTES) {     // 99,155,968
    char* ETt = ws;
    u16* pctx = (u16*)(ws + ETT_BYTES);
    float* pstat = (float*)(ws + ETT_BYTES + PCTX_BYTES);
    cvt3_kernel<<<VOCABSZ / 32, 256, 0, stream>>>(emb, ETt);
    flash15_kernel<4><<<256, 512, 0, stream>>>(q, ETt, out, pctx, pstat);
    combine2_kernel<<<NROWSZ, 256, 0, stream>>>(q, pctx, pstat, out);
  } else if (ws_size >= ETT_BYTES) {
    char* ETt = ws;
    cvt3_kernel<<<VOCABSZ / 32, 256, 0, stream>>>(emb, ETt);
    flash15_kernel<1><<<NROWSZ / MBLK, 512, 0, stream>>>(q, ETt, out, nullptr, nullptr);
  } else {
    naive_kernel<<<NROWSZ, 256, 0, stream>>>(q, emb, out);
  }
}